// Round 7
// baseline (164.416 us; speedup 1.0000x reference)
//
#include <hip/hip_runtime.h>
#include <hip/hip_bf16.h>

#define NB 2
#define NN 20000
#define NKN 16          // neighbors per node
#define NC 128          // C_IN
#define NM 9            // M kernels
#define NO 128          // C_OUT
#define NR (NB*NN)      // 40000 rows
#define KK (NM*NC)      // 1152 GEMM reduce dim
#define NKC (KK/32)     // 36 K-chunks of 32
#define NPB 16          // nodes per fused block
#define YS 12           // padded y row stride (floats) -> float4-aligned
#define QS (NKN*12+4)   // per-node q stride (floats): ≡4 mod 32 banks -> conflict-free

typedef short bf16x8 __attribute__((ext_vector_type(8)));
typedef float f32x4 __attribute__((ext_vector_type(4)));
typedef float f32x2 __attribute__((ext_vector_type(2)));
typedef unsigned short u16x8 __attribute__((ext_vector_type(8)));

__device__ inline f32x2 bfpair(unsigned int w) {   // [lo16, hi16] bf16 -> float2
    union { unsigned int u; float f; } lo, hi;
    lo.u = w << 16; hi.u = w & 0xFFFF0000u;
    return (f32x2){lo.f, hi.f};
}

// ---------------- Kernel 1: prep = ycalc (+xb emit) | wprep, by block range ----------
__global__ __launch_bounds__(256) void prep_kernel(const float* __restrict__ x,
                                                   const float* __restrict__ u,
                                                   const float* __restrict__ W,
                                                   float* __restrict__ y,
                                                   __hip_bfloat16* __restrict__ xb,
                                                   __hip_bfloat16* __restrict__ Wg,
                                                   int use_xb) {
    if (blockIdx.x < NR / 4) {
        __shared__ float u_l[NM * NC];
        for (int t = threadIdx.x; t < NM * NC; t += 256) u_l[t] = u[t];
        __syncthreads();
        int wave = threadIdx.x >> 6;
        int lane = threadIdx.x & 63;
        int node = blockIdx.x * 4 + wave;
        float xv0 = x[node * NC + lane];
        float xv1 = x[node * NC + 64 + lane];
        if (use_xb) {
            xb[node * NC + lane]      = __float2bfloat16(xv0);
            xb[node * NC + 64 + lane] = __float2bfloat16(xv1);
        }
        #pragma unroll
        for (int m = 0; m < NM; m++) {
            float p = xv0 * u_l[m * NC + lane] + xv1 * u_l[m * NC + 64 + lane];
            #pragma unroll
            for (int off = 32; off > 0; off >>= 1) p += __shfl_xor(p, off, 64);
            if (lane == 0) y[node * YS + m] = p;
        }
    } else {
        // Wg[((kk/32)*128 + o)*32 + (kk%32)] = bf16(W[m][o][c]), kk = m*128+c
        int t = (blockIdx.x - NR / 4) * 256 + threadIdx.x;   // t < 1152*128
        int kk = t >> 7;
        int o = t & 127;
        int m = kk >> 7;
        int c = kk & 127;
        float v = W[m * 16384 + o * 128 + c];
        Wg[((kk >> 5) * 128 + o) * 32 + (kk & 31)] = __float2bfloat16(v);
    }
}

// ---------------- Kernel 2: fused edge-softmax + aggregate + MFMA GEMM --------------
// Block = 16 nodes, 256 threads (4 waves), ~50.4KB LDS -> 3 blocks/CU.
// A1: adj -> s_adj; y rows loaded up front (drained by barrier 1).
// After barrier 1: idx/deg from s_adj, ALL 16 xb gathers issued (stay in flight),
//   then A2 softmax runs on already-loaded y (overlaps gather latency), q stored
//   pre-zeroed for padding edges. Barrier 2 drains gathers exactly at A3's use.
// A3: branch-free v_pk_fma accumulate -> S' in XOR-swizzled LDS (bf16).
// barrier 3 -> B: out[16x128] = S' x Wg + b, barrier-free MFMA, B-frags from L2.
template<bool BF16G>
__global__ __launch_bounds__(256, 3) void fused_kernel(const float* __restrict__ x,
                                                       const __hip_bfloat16* __restrict__ xb,
                                                       const int* __restrict__ adj,
                                                       const float* __restrict__ y,
                                                       const float* __restrict__ cv,
                                                       const __hip_bfloat16* __restrict__ Wg,
                                                       const float* __restrict__ bv,
                                                       float* __restrict__ out) {
    __shared__ __align__(16) short s_S[NPB * KK];  // 36,864 B, swizzled granules
    __shared__ int   s_adj[NPB][NKN];              //  1,024 B
    __shared__ __align__(16) float s_q[NPB][QS];   // 12,544 B

    int tid = threadIdx.x;
    int node0 = blockIdx.x * NPB;
    int b = node0 / NN;
    int n0 = node0 - b * NN;
    int ln = tid >> 4, k = tid & 15;               // 256 = 16 nodes x 16 edges

    // ---- A1: own adj element + y row loads (in flight; drained by barrier 1) ----
    int a = adj[(n0 + ln) * NKN + k];
    const float* yn = y + (long)(node0 + ln) * YS;
    const float* ya = y + (long)(b * NN + ((a > 0) ? a - 1 : 0)) * YS;
    float4 yn0 = *(const float4*)yn;
    float4 yn1 = *(const float4*)(yn + 4);
    float  yn8 = yn[8];
    float4 ya0 = *(const float4*)ya;
    float4 ya1 = *(const float4*)(ya + 4);
    float  ya8 = ya[8];
    s_adj[ln][k] = a;
    __syncthreads();                               // barrier 1 (drains y loads too)

    // ---- idx/deg for this node; issue ALL 16 gathers (BF16G path) ----
    int c8 = k << 3;
    int idx[NKN]; int d = 0;
    #pragma unroll
    for (int j = 0; j < NKN; j++) {
        int aa = s_adj[ln][j];
        d += (aa > 0);
        idx[j] = (aa > 0) ? aa - 1 : 0;            // safe index; q=0 kills contribution
    }
    float di = (d > 0) ? 1.f / (float)d : 0.f;

    uint4 pw[NKN];
    if (BF16G) {
        #pragma unroll
        for (int j = 0; j < NKN; j++)
            pw[j] = *(const uint4*)((const unsigned short*)xb +
                                    (long)(b * NN + idx[j]) * NC + c8);
    }

    // ---- A2: softmax on pre-loaded y (overlaps the gathers' latency) ----
    {
        float sel = (a > 0) ? 1.f : 0.f;
        float l[NM];
        l[0] = yn0.x - sel * ya0.x + cv[0];
        l[1] = yn0.y - sel * ya0.y + cv[1];
        l[2] = yn0.z - sel * ya0.z + cv[2];
        l[3] = yn0.w - sel * ya0.w + cv[3];
        l[4] = yn1.x - sel * ya1.x + cv[4];
        l[5] = yn1.y - sel * ya1.y + cv[5];
        l[6] = yn1.z - sel * ya1.z + cv[6];
        l[7] = yn1.w - sel * ya1.w + cv[7];
        l[8] = yn8   - sel * ya8   + cv[8];
        float mx = l[0];
        #pragma unroll
        for (int m = 1; m < NM; m++) mx = fmaxf(mx, l[m]);
        float e[NM]; float sum = 0.f;
        #pragma unroll
        for (int m = 0; m < NM; m++) { e[m] = expf(l[m] - mx); sum += e[m]; }
        float qs = (a > 0) ? (1.f / sum) : 0.f;    // padding edge -> q == 0
        #pragma unroll
        for (int m = 0; m < NM; m++) s_q[ln][k * 12 + m] = e[m] * qs;
    }
    __syncthreads();                               // barrier 2 (drains gathers)

    // ---- A3: branch-free accumulate (v_pk_fma_f32 via float2) ----
    {
        f32x2 s2[NM][4];
        #pragma unroll
        for (int m = 0; m < NM; m++)
            #pragma unroll
            for (int j = 0; j < 4; j++) s2[m][j] = (f32x2){0.f, 0.f};

        if (BF16G) {
            #pragma unroll
            for (int kk2 = 0; kk2 < NKN; kk2++) {
                f32x2 p0 = bfpair(pw[kk2].x), p1 = bfpair(pw[kk2].y);
                f32x2 p2 = bfpair(pw[kk2].z), p3 = bfpair(pw[kk2].w);
                const float* qr = &s_q[ln][kk2 * 12];
                float4 qa = *(const float4*)qr;
                float4 qb = *(const float4*)(qr + 4);
                float  q8 = qr[8];
                #define ACC(mi, qv) { f32x2 qq = (f32x2){(qv), (qv)};           \
                    s2[mi][0] += qq * p0; s2[mi][1] += qq * p1;                 \
                    s2[mi][2] += qq * p2; s2[mi][3] += qq * p3; }
                ACC(0, qa.x) ACC(1, qa.y) ACC(2, qa.z) ACC(3, qa.w)
                ACC(4, qb.x) ACC(5, qb.y) ACC(6, qb.z) ACC(7, qb.w) ACC(8, q8)
                #undef ACC
            }
        } else {
            #pragma unroll
            for (int g = 0; g < NKN / 4; g++) {
                float4 fa[4], fb[4];
                #pragma unroll
                for (int j = 0; j < 4; j++) {
                    const float* px = x + (long)(b * NN + idx[g * 4 + j]) * NC + c8;
                    fa[j] = *(const float4*)px;
                    fb[j] = *(const float4*)(px + 4);
                }
                #pragma unroll
                for (int j = 0; j < 4; j++) {
                    int kk2 = g * 4 + j;
                    f32x2 p0 = (f32x2){fa[j].x, fa[j].y}, p1 = (f32x2){fa[j].z, fa[j].w};
                    f32x2 p2 = (f32x2){fb[j].x, fb[j].y}, p3 = (f32x2){fb[j].z, fb[j].w};
                    const float* qr = &s_q[ln][kk2 * 12];
                    float4 qa = *(const float4*)qr;
                    float4 qb = *(const float4*)(qr + 4);
                    float  q8 = qr[8];
                    #define ACC(mi, qv) { f32x2 qq = (f32x2){(qv), (qv)};       \
                        s2[mi][0] += qq * p0; s2[mi][1] += qq * p1;             \
                        s2[mi][2] += qq * p2; s2[mi][3] += qq * p3; }
                    ACC(0, qa.x) ACC(1, qa.y) ACC(2, qa.z) ACC(3, qa.w)
                    ACC(4, qb.x) ACC(5, qb.y) ACC(6, qb.z) ACC(7, qb.w) ACC(8, q8)
                    #undef ACC
                }
            }
        }

        #pragma unroll
        for (int m = 0; m < NM; m++) {
            u16x8 ov;
            #pragma unroll
            for (int j = 0; j < 4; j++) {
                union { unsigned short h; __hip_bfloat16 bb; } c0, c1;
                c0.bb = __float2bfloat16(s2[m][j][0] * di);
                c1.bb = __float2bfloat16(s2[m][j][1] * di);
                ov[j * 2]     = c0.h;
                ov[j * 2 + 1] = c1.h;
            }
            int g = m * 16 + k;                    // 16B granule index within row
            int gs = g ^ (ln & 7);                 // XOR swizzle -> bank spread
            *(u16x8*)(&s_S[ln * KK + gs * 8]) = ov;
        }
    }
    __syncthreads();                               // barrier 3: S' ready

    // ---------------- phase B: GEMM 16x1152 @ 1152x128, barrier-free ----------------
    int wave = tid >> 6;
    int lane = tid & 63;
    int lr = lane & 15;        // A row / B col-in-tile
    int quad = lane >> 4;      // k-group
    const short* wg = reinterpret_cast<const short*>(Wg);
    f32x4 acc0 = (f32x4){0.f,0.f,0.f,0.f};
    f32x4 acc1 = (f32x4){0.f,0.f,0.f,0.f};
    int ct0 = wave * 2;        // this wave's col-tiles: ct0, ct0+1

    #pragma unroll 9
    for (int kc = 0; kc < NKC; kc++) {
        int g = kc * 4 + quad;                     // A granule
        int gs = g ^ (lr & 7);
        bf16x8 afrag = *(const bf16x8*)(&s_S[lr * KK + gs * 8]);
        bf16x8 b0 = *(const bf16x8*)(wg + ((kc * 128) + ct0 * 16 + lr) * 32 + quad * 8);
        bf16x8 b1 = *(const bf16x8*)(wg + ((kc * 128) + (ct0 + 1) * 16 + lr) * 32 + quad * 8);
        acc0 = __builtin_amdgcn_mfma_f32_16x16x32_bf16(afrag, b0, acc0, 0, 0, 0);
        acc1 = __builtin_amdgcn_mfma_f32_16x16x32_bf16(afrag, b1, acc1, 0, 0, 0);
    }

    // epilogue: D row = quad*4 + r, col = ct*16 + lr
    int col0 = ct0 * 16 + lr;
    int col1 = col0 + 16;
    float bb0 = bv[col0];
    float bb1 = bv[col1];
    int rbase = node0 + quad * 4;
    #pragma unroll
    for (int r = 0; r < 4; r++) {
        out[(long)(rbase + r) * NO + col0] = acc0[r] + bb0;
        out[(long)(rbase + r) * NO + col1] = acc1[r] + bb1;
    }
}

extern "C" void kernel_launch(void* const* d_in, const int* in_sizes, int n_in,
                              void* d_out, int out_size, void* d_ws, size_t ws_size,
                              hipStream_t stream) {
    const float* x   = (const float*)d_in[0];   // (B,N,C)
    const int*   adj = (const int*)  d_in[1];   // (N,K)
    const float* W   = (const float*)d_in[2];   // (M,O,C)
    const float* bv  = (const float*)d_in[3];   // (O,)
    const float* u   = (const float*)d_in[4];   // (M,C)
    const float* cv  = (const float*)d_in[5];   // (M,)
    float* out = (float*)d_out;

    char* ws = (char*)d_ws;
    float* y = (float*)ws;                                     // 40000*12*4 = 1,920,000 B
    __hip_bfloat16* Wg = (__hip_bfloat16*)(ws + 1920000);      //   294,912 B
    __hip_bfloat16* xb = (__hip_bfloat16*)(ws + 2214912);      // 10,240,000 B (16B-aligned)
    bool use_xb = (ws_size >= (size_t)12454912);

    prep_kernel<<<NR / 4 + 576, 256, 0, stream>>>(x, u, W, y, use_xb ? xb : nullptr, Wg,
                                                  use_xb ? 1 : 0);
    if (use_xb)
        fused_kernel<true><<<NR / NPB, 256, 0, stream>>>(x, xb, adj, y, cv, Wg, bv, out);
    else
        fused_kernel<false><<<NR / NPB, 256, 0, stream>>>(x, xb, adj, y, cv, Wg, bv, out);
}